// Round 16
// baseline (598.469 us; speedup 1.0000x reference)
//
#include <hip/hip_runtime.h>
#include <hip/hip_bf16.h>
#include <hip/hip_cooperative_groups.h>

namespace cg = cooperative_groups;

#define N_NODES 50000
#define N_EDGES 800000
#define N_RELS  32
#define D       64
#define TILE_M  128
#define NBKT    196                         // ceil(50000/256) dst buckets
#define EPB     2048                        // edges per virtual block in kC
#define NEBLK   ((N_EDGES + EPB - 1) / EPB) // 391
#define SEGCAP  27008                       // per-rel fixed cap (211*128)
#define CAPB    4608                        // per-bucket fixed cap
#define NT_MAX  (N_RELS * (SEGCAP / TILE_M))
#define FEATH_BLKS ((N_NODES * D / 8 + 255) / 256)   // 1563
#define MEGA_BLOCKS 1024                    // 4 blocks/CU guaranteed co-resident

typedef _Float16 half8 __attribute__((ext_vector_type(8)));
typedef float    f32x4 __attribute__((ext_vector_type(4)));

// ---------------- workspace layout (bytes) — round-15 layout ----------------
#define OFF_RELCUR  0u          // 32 int
#define OFF_BKTCUR  128u        // 196 int
#define OFF_TB      912u        // 33 int
#define OFF_DSTOFF  1056u       // 50000 int
#define OFF_RELSRC  201056u     // 864256 int
#define OFF_CSRY    3658080u    // 903168 int
#define OFF_BUCK    7270752u    // 903168 int
#define OFF_WT      10883424u   // 32*64*64 fp16
#define OFF_FEATH   11145568u   // 50000*64 fp16
#define OFF_Y_FULL  17545568u   // 864256*64 fp16, rel-contiguous
#define OFF_Y_BASE  11145568u
#define WS_H        128170336u
#define WS_B        121770336u

// ---------------- fallback: atomic scatter path ----------------
__global__ __launch_bounds__(256) void rgcn_edge_atomic(
    const float* __restrict__ feat, const float* __restrict__ weight,
    const int* __restrict__ src, const int* __restrict__ dst,
    const int* __restrict__ et, float* __restrict__ out, int nquads)
{
    const int tid  = blockIdx.x * blockDim.x + threadIdx.x;
    const int wave = tid >> 6, lane = tid & 63;
    const int grp = lane >> 4, lg = lane & 15;
    const int wave_stride = (gridDim.x * blockDim.x) >> 6;
    for (int q = wave; q < nquads; q += wave_stride) {
        const int e = q * 4 + grp;
        const int s = src[e], d = dst[e], r = et[e];
        const float* w = weight + (size_t)r * D * D + lg * 4;
        float ax = 0.f, ay = 0.f, az = 0.f, aw = 0.f;
        #pragma unroll
        for (int i4 = 0; i4 < D / 4; ++i4) {
            const float4 f  = *reinterpret_cast<const float4*>(feat + (size_t)s * D + i4 * 4);
            const float4 w0 = *reinterpret_cast<const float4*>(w + (i4 * 4 + 0) * D);
            const float4 w1 = *reinterpret_cast<const float4*>(w + (i4 * 4 + 1) * D);
            const float4 w2 = *reinterpret_cast<const float4*>(w + (i4 * 4 + 2) * D);
            const float4 w3 = *reinterpret_cast<const float4*>(w + (i4 * 4 + 3) * D);
            ax += f.x*w0.x; ay += f.x*w0.y; az += f.x*w0.z; aw += f.x*w0.w;
            ax += f.y*w1.x; ay += f.y*w1.y; az += f.y*w1.z; aw += f.y*w1.w;
            ax += f.z*w2.x; ay += f.z*w2.y; az += f.z*w2.z; aw += f.z*w2.w;
            ax += f.w*w3.x; ay += f.w*w3.y; az += f.w*w3.z; aw += f.w*w3.w;
        }
        float* orow = out + (size_t)d * D + lg * 4;
        atomicAdd(orow + 0, ax); atomicAdd(orow + 1, ay);
        atomicAdd(orow + 2, az); atomicAdd(orow + 3, aw);
    }
}

// ============ standalone kernels (fallback path, round-15 proven) ============
__global__ __launch_bounds__(256) void kPre(const float* __restrict__ w,
                                            _Float16* __restrict__ wT,
                                            const float* __restrict__ feat,
                                            _Float16* __restrict__ featH,
                                            int* __restrict__ relcur,
                                            int* __restrict__ bktcur)
{
    const int t = threadIdx.x;
    if (blockIdx.x < N_RELS) {
        if (blockIdx.x == 0) {
            if (t < N_RELS)                relcur[t] = t * SEGCAP;
            else if (t < N_RELS + NBKT)    bktcur[t - N_RELS] = (t - N_RELS) * CAPB;
        }
        const int r = blockIdx.x;
        #pragma unroll
        for (int i = 0; i < 16; ++i) {
            int oidx = i * 256 + t;
            int o = oidx >> 6, k = oidx & 63;
            wT[(size_t)r * 4096 + oidx] = (_Float16)w[(size_t)r * 4096 + k * 64 + o];
        }
    } else {
        const int base = ((blockIdx.x - N_RELS) * 256 + t) * 8;
        if (base >= N_NODES * D) return;
        float4 f0 = *reinterpret_cast<const float4*>(feat + base);
        float4 f1 = *reinterpret_cast<const float4*>(feat + base + 4);
        half8 h;
        h[0]=(_Float16)f0.x; h[1]=(_Float16)f0.y; h[2]=(_Float16)f0.z; h[3]=(_Float16)f0.w;
        h[4]=(_Float16)f1.x; h[5]=(_Float16)f1.y; h[6]=(_Float16)f1.z; h[7]=(_Float16)f1.w;
        *reinterpret_cast<half8*>(featH + base) = h;
    }
}

__global__ __launch_bounds__(256) void kC_scatter(const int* __restrict__ src,
                                                  const int* __restrict__ dst,
                                                  const int* __restrict__ et,
                                                  int* __restrict__ relcur,
                                                  int* __restrict__ bktcur,
                                                  int* __restrict__ relsrc,
                                                  int* __restrict__ bucketed)
{
    __shared__ int lh[N_RELS],  lbase[N_RELS];
    __shared__ int lb[NBKT],    lbase2[NBKT];
    const int t = threadIdx.x;
    if (t < N_RELS) lh[t] = 0;
    if (t < NBKT)   lb[t] = 0;
    __syncthreads();
    const int base = blockIdx.x * EPB + t * 8;
    int r_[8], b_[8], s_[8], d_[8], sl[8], sl2[8];
    #pragma unroll
    for (int i = 0; i < 8; ++i) {
        int e = base + i;
        if (e < N_EDGES) {
            r_[i] = et[e]; s_[i] = src[e]; d_[i] = dst[e];
            b_[i] = d_[i] >> 8;
            sl[i]  = atomicAdd(&lh[r_[i]], 1);
            sl2[i] = atomicAdd(&lb[b_[i]], 1);
        }
    }
    __syncthreads();
    if (t < N_RELS && lh[t]) lbase[t]  = atomicAdd(&relcur[t], lh[t]);
    if (t < NBKT   && lb[t]) lbase2[t] = atomicAdd(&bktcur[t], lb[t]);
    __syncthreads();
    #pragma unroll
    for (int i = 0; i < 8; ++i) {
        int e = base + i;
        if (e < N_EDGES) {
            int j    = lbase[r_[i]] + sl[i];
            int pos2 = lbase2[b_[i]] + sl2[i];
            if (j < N_RELS * SEGCAP) relsrc[j] = s_[i];
            if (pos2 < NBKT * CAPB)
                bucketed[pos2] = ((d_[i] & 255) << 20) | j;
        }
    }
}

__global__ __launch_bounds__(256) void kD_csr(const int* __restrict__ bucketed,
                                              const int* __restrict__ bktcur,
                                              const int* __restrict__ relcur,
                                              int* __restrict__ csr_y,
                                              int* __restrict__ dst_off,
                                              int* __restrict__ tb)
{
    __shared__ int hist[256];
    __shared__ int s[256];
    const int b = blockIdx.x, t = threadIdx.x;
    if (b == NBKT) {
        int c = 0, w = 0;
        if (t < N_RELS) {
            c = min(relcur[t] - t * SEGCAP, SEGCAP);
            w = (c + TILE_M - 1) >> 7;
        }
        s[t] = (t < N_RELS) ? w : 0; __syncthreads();
        #pragma unroll
        for (int off = 1; off < N_RELS; off <<= 1) {
            int u = (t >= off && t < N_RELS) ? s[t - off] : 0;
            __syncthreads(); s[t] += u; __syncthreads();
        }
        if (t < N_RELS) tb[t] = s[t] - w;
        if (t == N_RELS - 1) tb[N_RELS] = s[t];
        return;
    }
    const int lo = b * CAPB;
    const int hi = min(bktcur[b], lo + CAPB);
    hist[t] = 0; __syncthreads();
    for (int p = lo + t; p < hi; p += 256)
        atomicAdd(&hist[bucketed[p] >> 20], 1);
    __syncthreads();
    int v = hist[t];
    s[t] = v; __syncthreads();
    #pragma unroll
    for (int off = 1; off < 256; off <<= 1) {
        int u = (t >= off) ? s[t - off] : 0;
        __syncthreads(); s[t] += u; __syncthreads();
    }
    int ex = lo + s[t] - v;
    int n = b * 256 + t;
    if (n < N_NODES) dst_off[n] = ex;
    hist[t] = ex;
    __syncthreads();
    for (int p = lo + t; p < hi; p += 256) {
        int key = bucketed[p];
        int pos = atomicAdd(&hist[key >> 20], 1);
        csr_y[pos] = key & 0xFFFFF;
    }
}

template <bool USE_H>
__global__ __launch_bounds__(256) void k4_gemm(const float* __restrict__ feat,
                                               const _Float16* __restrict__ featH,
                                               const _Float16* __restrict__ wT,
                                               const int* __restrict__ relsrc,
                                               const int* __restrict__ relcur,
                                               const int* __restrict__ tb,
                                               _Float16* __restrict__ Y)
{
    __shared__ _Float16 wL[64 * 64];
    const int b = blockIdx.x, t = threadIdx.x;
    int r = -1, ti = 0, t0 = 0;
    #pragma unroll
    for (int q = 0; q < N_RELS; ++q) {
        int t1 = tb[q + 1];
        if (b >= t0 && b < t1) { r = q; ti = b - t0; }
        t0 = t1;
    }
    if (r < 0) return;
    const int segend  = min(relcur[r], (r + 1) * SEGCAP);
    const int rowbase = r * SEGCAP + ti * TILE_M;
    {
        const _Float16* wsrc = wT + (size_t)r * 4096;
        #pragma unroll
        for (int it = 0; it < 2; ++it) {
            int L8 = it * 256 + t;
            int o = L8 >> 3, kcol = (L8 & 7) * 8;
            int baddr = (o * 128 + kcol * 2) ^ ((o & 7) << 4);
            *reinterpret_cast<half8*>(reinterpret_cast<char*>(wL) + baddr) =
                *reinterpret_cast<const half8*>(wsrc + L8 * 8);
        }
    }
    const int wid = t >> 6, l = t & 63;
    const int lrow = l & 15, lkb = l >> 4;
    half8 af[2][2];
    #pragma unroll
    for (int rt = 0; rt < 2; ++rt) {
        const int row = wid * 32 + rt * 16 + lrow;
        const int j = rowbase + row;
        const int sidx = (j < segend) ? relsrc[j] : 0;
        if (USE_H) {
            const _Float16* ar = featH + ((size_t)sidx << 6) + lkb * 8;
            af[rt][0] = *reinterpret_cast<const half8*>(ar);
            af[rt][1] = *reinterpret_cast<const half8*>(ar + 32);
        } else {
            const float* ar = feat + ((size_t)sidx << 6) + lkb * 8;
            float4 a0 = *reinterpret_cast<const float4*>(ar);
            float4 a1 = *reinterpret_cast<const float4*>(ar + 4);
            float4 a2 = *reinterpret_cast<const float4*>(ar + 32);
            float4 a3 = *reinterpret_cast<const float4*>(ar + 36);
            half8 h0, h1;
            h0[0]=(_Float16)a0.x; h0[1]=(_Float16)a0.y; h0[2]=(_Float16)a0.z; h0[3]=(_Float16)a0.w;
            h0[4]=(_Float16)a1.x; h0[5]=(_Float16)a1.y; h0[6]=(_Float16)a1.z; h0[7]=(_Float16)a1.w;
            h1[0]=(_Float16)a2.x; h1[1]=(_Float16)a2.y; h1[2]=(_Float16)a2.z; h1[3]=(_Float16)a2.w;
            h1[4]=(_Float16)a3.x; h1[5]=(_Float16)a3.y; h1[6]=(_Float16)a3.z; h1[7]=(_Float16)a3.w;
            af[rt][0] = h0; af[rt][1] = h1;
        }
    }
    __syncthreads();
    f32x4 acc[2][4] = {};
    #pragma unroll
    for (int ks = 0; ks < 2; ++ks) {
        half8 bfr[4];
        #pragma unroll
        for (int ct = 0; ct < 4; ++ct) {
            int n = ct * 16 + lrow;
            int baddr = (n * 128 + ks * 64 + lkb * 16) ^ ((n & 7) << 4);
            bfr[ct] = *reinterpret_cast<const half8*>(reinterpret_cast<const char*>(wL) + baddr);
        }
        #pragma unroll
        for (int rt = 0; rt < 2; ++rt)
            #pragma unroll
            for (int ct = 0; ct < 4; ++ct)
                acc[rt][ct] = __builtin_amdgcn_mfma_f32_16x16x32_f16(af[rt][ks], bfr[ct], acc[rt][ct], 0, 0, 0);
    }
    #pragma unroll
    for (int rt = 0; rt < 2; ++rt) {
        int lrow0 = wid * 32 + rt * 16 + (l >> 4) * 4;
        #pragma unroll
        for (int reg = 0; reg < 4; ++reg) {
            int lr = lrow0 + reg;
            int j = rowbase + lr;
            if (j < segend) {
                size_t yrow = (size_t)j * 64;
                #pragma unroll
                for (int ct = 0; ct < 4; ++ct)
                    Y[yrow + ct * 16 + lrow] = (_Float16)acc[rt][ct][reg];
            }
        }
    }
}

__global__ __launch_bounds__(256) void k5_reduce(const _Float16* __restrict__ Y,
                                                 const int* __restrict__ csr_y,
                                                 const int* __restrict__ dst_off,
                                                 const int* __restrict__ bktcur,
                                                 float* __restrict__ out)
{
    const int wid = threadIdx.x >> 6, l = threadIdx.x & 63;
    const int n = blockIdx.x * 4 + wid;
    if (n >= N_NODES) return;
    const int b = n >> 8;
    const int p0 = dst_off[n];
    int p1 = ((n & 255) == 255 || n == N_NODES - 1) ? bktcur[b] : dst_off[n + 1];
    p1 = min(p1, (b + 1) * CAPB);
    const int rg = l >> 3;
    const int cg = l & 7;
    float a[8] = {0,0,0,0,0,0,0,0};
    for (int p = p0; p < p1; p += 8) {
        int q = p + rg;
        if (q < p1) {
            int j = csr_y[q];
            half8 v = *reinterpret_cast<const half8*>(Y + (size_t)j * 64 + cg * 8);
            #pragma unroll
            for (int i = 0; i < 8; ++i) a[i] += (float)v[i];
        }
    }
    #pragma unroll
    for (int m = 8; m < 64; m <<= 1)
        #pragma unroll
        for (int i = 0; i < 8; ++i)
            a[i] += __shfl_xor(a[i], m, 64);
    if (rg == 0) {
        float* orow = out + (size_t)n * 64 + cg * 8;
        f32x4 v0 = {a[0], a[1], a[2], a[3]};
        f32x4 v1 = {a[4], a[5], a[6], a[7]};
        *reinterpret_cast<f32x4*>(orow)     = v0;
        *reinterpret_cast<f32x4*>(orow + 4) = v1;
    }
}

// ============ cooperative mega-kernel: all 5 phases, 4 grid syncs ============
template <bool USE_H>
__global__ __launch_bounds__(256, 4) void mega(
    const float* __restrict__ feat, const float* __restrict__ weight,
    const int* __restrict__ src, const int* __restrict__ dst, const int* __restrict__ et,
    _Float16* __restrict__ wT, _Float16* __restrict__ featH,
    int* __restrict__ relcur, int* __restrict__ bktcur,
    int* __restrict__ relsrc, int* __restrict__ bucketed,
    int* __restrict__ csr_y, int* __restrict__ dst_off, int* __restrict__ tb,
    _Float16* __restrict__ Y, float* __restrict__ out)
{
    cg::grid_group grid = cg::this_grid();
    const int t = threadIdx.x;
    __shared__ _Float16 wL[64 * 64];                 // 8 KB, unioned across phases
    int* ish = reinterpret_cast<int*>(wL);

    // ---- phase 1: cursors + wT transpose + featH convert ----
    const int pre_blocks = N_RELS + (USE_H ? FEATH_BLKS : 0);
    for (int b = blockIdx.x; b < pre_blocks; b += gridDim.x) {
        if (b < N_RELS) {
            if (b == 0) {
                if (t < N_RELS)             relcur[t] = t * SEGCAP;
                else if (t < N_RELS + NBKT) bktcur[t - N_RELS] = (t - N_RELS) * CAPB;
            }
            #pragma unroll
            for (int i = 0; i < 16; ++i) {
                int oidx = i * 256 + t;
                int o = oidx >> 6, k = oidx & 63;
                wT[(size_t)b * 4096 + oidx] = (_Float16)weight[(size_t)b * 4096 + k * 64 + o];
            }
        } else if (USE_H) {
            const int base = ((b - N_RELS) * 256 + t) * 8;
            if (base < N_NODES * D) {
                float4 f0 = *reinterpret_cast<const float4*>(feat + base);
                float4 f1 = *reinterpret_cast<const float4*>(feat + base + 4);
                half8 h;
                h[0]=(_Float16)f0.x; h[1]=(_Float16)f0.y; h[2]=(_Float16)f0.z; h[3]=(_Float16)f0.w;
                h[4]=(_Float16)f1.x; h[5]=(_Float16)f1.y; h[6]=(_Float16)f1.z; h[7]=(_Float16)f1.w;
                *reinterpret_cast<half8*>(featH + base) = h;
            }
        }
    }
    grid.sync();

    // ---- phase 2: scatter (rel segments + dst buckets) ----
    {
        int* lh  = ish;        int* lbA = ish + 32;
        int* lb  = ish + 64;   int* lbB = ish + 64 + NBKT;
        for (int b = blockIdx.x; b < NEBLK; b += gridDim.x) {
            __syncthreads();
            if (t < N_RELS) lh[t] = 0;
            if (t < NBKT)   lb[t] = 0;
            __syncthreads();
            const int base = b * EPB + t * 8;
            int r_[8], bb[8], s_[8], d_[8], sl[8], sl2[8];
            #pragma unroll
            for (int i = 0; i < 8; ++i) {
                int e = base + i;
                if (e < N_EDGES) {
                    r_[i] = et[e]; s_[i] = src[e]; d_[i] = dst[e];
                    bb[i] = d_[i] >> 8;
                    sl[i]  = atomicAdd(&lh[r_[i]], 1);
                    sl2[i] = atomicAdd(&lb[bb[i]], 1);
                }
            }
            __syncthreads();
            if (t < N_RELS && lh[t]) lbA[t] = atomicAdd(&relcur[t], lh[t]);
            if (t < NBKT   && lb[t]) lbB[t] = atomicAdd(&bktcur[t], lb[t]);
            __syncthreads();
            #pragma unroll
            for (int i = 0; i < 8; ++i) {
                int e = base + i;
                if (e < N_EDGES) {
                    int j    = lbA[r_[i]] + sl[i];
                    int pos2 = lbB[bb[i]] + sl2[i];
                    if (j < N_RELS * SEGCAP) relsrc[j] = s_[i];
                    if (pos2 < NBKT * CAPB)
                        bucketed[pos2] = ((d_[i] & 255) << 20) | j;
                }
            }
        }
    }
    grid.sync();

    // ---- phase 3: per-bucket counting sort -> csr_y/dst_off; +tile scan ----
    {
        int* hist = ish; int* s = ish + 256;
        for (int b = blockIdx.x; b < NBKT + 1; b += gridDim.x) {
            __syncthreads();
            if (b == NBKT) {
                int c = 0, w = 0;
                if (t < N_RELS) {
                    c = min(relcur[t] - t * SEGCAP, SEGCAP);
                    w = (c + TILE_M - 1) >> 7;
                }
                s[t] = (t < N_RELS) ? w : 0; __syncthreads();
                #pragma unroll
                for (int off = 1; off < N_RELS; off <<= 1) {
                    int u = (t >= off && t < N_RELS) ? s[t - off] : 0;
                    __syncthreads(); s[t] += u; __syncthreads();
                }
                if (t < N_RELS) tb[t] = s[t] - w;
                if (t == N_RELS - 1) tb[N_RELS] = s[t];
            } else {
                const int lo = b * CAPB;
                const int hi = min(bktcur[b], lo + CAPB);
                hist[t] = 0; __syncthreads();
                for (int p = lo + t; p < hi; p += 256)
                    atomicAdd(&hist[bucketed[p] >> 20], 1);
                __syncthreads();
                int v = hist[t];
                s[t] = v; __syncthreads();
                #pragma unroll
                for (int off = 1; off < 256; off <<= 1) {
                    int u = (t >= off) ? s[t - off] : 0;
                    __syncthreads(); s[t] += u; __syncthreads();
                }
                int ex = lo + s[t] - v;
                int n = b * 256 + t;
                if (n < N_NODES) dst_off[n] = ex;
                hist[t] = ex;
                __syncthreads();
                for (int p = lo + t; p < hi; p += 256) {
                    int key = bucketed[p];
                    int pos = atomicAdd(&hist[key >> 20], 1);
                    csr_y[pos] = key & 0xFFFFF;
                }
            }
        }
    }
    grid.sync();

    // ---- phase 4: per-relation MFMA GEMM -> Y (rel-contiguous) ----
    {
        const int tsum = tb[N_RELS];
        const int wid = t >> 6, l = t & 63;
        const int lrow = l & 15, lkb = l >> 4;
        for (int b = blockIdx.x; b < tsum; b += gridDim.x) {
            __syncthreads();
            int r = -1, ti = 0, t0 = 0;
            #pragma unroll
            for (int q = 0; q < N_RELS; ++q) {
                int t1 = tb[q + 1];
                if (b >= t0 && b < t1) { r = q; ti = b - t0; }
                t0 = t1;
            }
            if (r < 0) continue;
            const int segend  = min(relcur[r], (r + 1) * SEGCAP);
            const int rowbase = r * SEGCAP + ti * TILE_M;
            {
                const _Float16* wsrc = wT + (size_t)r * 4096;
                #pragma unroll
                for (int it = 0; it < 2; ++it) {
                    int L8 = it * 256 + t;
                    int o = L8 >> 3, kcol = (L8 & 7) * 8;
                    int baddr = (o * 128 + kcol * 2) ^ ((o & 7) << 4);
                    *reinterpret_cast<half8*>(reinterpret_cast<char*>(wL) + baddr) =
                        *reinterpret_cast<const half8*>(wsrc + L8 * 8);
                }
            }
            half8 af[2][2];
            #pragma unroll
            for (int rt = 0; rt < 2; ++rt) {
                const int row = wid * 32 + rt * 16 + lrow;
                const int j = rowbase + row;
                const int sidx = (j < segend) ? relsrc[j] : 0;
                if (USE_H) {
                    const _Float16* ar = featH + ((size_t)sidx << 6) + lkb * 8;
                    af[rt][0] = *reinterpret_cast<const half8*>(ar);
                    af[rt][1] = *reinterpret_cast<const half8*>(ar + 32);
                } else {
                    const float* ar = feat + ((size_t)sidx << 6) + lkb * 8;
                    float4 a0 = *reinterpret_cast<const float4*>(ar);
                    float4 a1 = *reinterpret_cast<const float4*>(ar + 4);
                    float4 a2 = *reinterpret_cast<const float4*>(ar + 32);
                    float4 a3 = *reinterpret_cast<const float4*>(ar + 36);
                    half8 h0, h1;
                    h0[0]=(_Float16)a0.x; h0[1]=(_Float16)a0.y; h0[2]=(_Float16)a0.z; h0[3]=(_Float16)a0.w;
                    h0[4]=(_Float16)a1.x; h0[5]=(_Float16)a1.y; h0[6]=(_Float16)a1.z; h0[7]=(_Float16)a1.w;
                    h1[0]=(_Float16)a2.x; h1[1]=(_Float16)a2.y; h1[2]=(_Float16)a2.z; h1[3]=(_Float16)a2.w;
                    h1[4]=(_Float16)a3.x; h1[5]=(_Float16)a3.y; h1[6]=(_Float16)a3.z; h1[7]=(_Float16)a3.w;
                    af[rt][0] = h0; af[rt][1] = h1;
                }
            }
            __syncthreads();
            f32x4 acc[2][4] = {};
            #pragma unroll
            for (int ks = 0; ks < 2; ++ks) {
                half8 bfr[4];
                #pragma unroll
                for (int ct = 0; ct < 4; ++ct) {
                    int n = ct * 16 + lrow;
                    int baddr = (n * 128 + ks * 64 + lkb * 16) ^ ((n & 7) << 4);
                    bfr[ct] = *reinterpret_cast<const half8*>(reinterpret_cast<const char*>(wL) + baddr);
                }
                #pragma unroll
                for (int rt = 0; rt < 2; ++rt)
                    #pragma unroll
                    for (int ct = 0; ct < 4; ++ct)
                        acc[rt][ct] = __builtin_amdgcn_mfma_f32_16x16x32_f16(af[rt][ks], bfr[ct], acc[rt][ct], 0, 0, 0);
            }
            #pragma unroll
            for (int rt = 0; rt < 2; ++rt) {
                int lrow0 = wid * 32 + rt * 16 + (l >> 4) * 4;
                #pragma unroll
                for (int reg = 0; reg < 4; ++reg) {
                    int lr = lrow0 + reg;
                    int j = rowbase + lr;
                    if (j < segend) {
                        size_t yrow = (size_t)j * 64;
                        #pragma unroll
                        for (int ct = 0; ct < 4; ++ct)
                            Y[yrow + ct * 16 + lrow] = (_Float16)acc[rt][ct][reg];
                    }
                }
            }
        }
    }
    grid.sync();

    // ---- phase 5: csr-indirect reduce -> out ----
    {
        const int wid = t >> 6, l = t & 63;
        const int rg = l >> 3, cg2 = l & 7;
        const int nvb = (N_NODES + 3) / 4;
        for (int vb = blockIdx.x; vb < nvb; vb += gridDim.x) {
            const int n = vb * 4 + wid;
            if (n >= N_NODES) continue;
            const int bkt = n >> 8;
            const int p0 = dst_off[n];
            int p1 = ((n & 255) == 255 || n == N_NODES - 1) ? bktcur[bkt] : dst_off[n + 1];
            p1 = min(p1, (bkt + 1) * CAPB);
            float a[8] = {0,0,0,0,0,0,0,0};
            for (int p = p0; p < p1; p += 8) {
                int q = p + rg;
                if (q < p1) {
                    int j = csr_y[q];
                    half8 v = *reinterpret_cast<const half8*>(Y + (size_t)j * 64 + cg2 * 8);
                    #pragma unroll
                    for (int i = 0; i < 8; ++i) a[i] += (float)v[i];
                }
            }
            #pragma unroll
            for (int m = 8; m < 64; m <<= 1)
                #pragma unroll
                for (int i = 0; i < 8; ++i)
                    a[i] += __shfl_xor(a[i], m, 64);
            if (rg == 0) {
                float* orow = out + (size_t)n * 64 + cg2 * 8;
                f32x4 v0 = {a[0], a[1], a[2], a[3]};
                f32x4 v1 = {a[4], a[5], a[6], a[7]};
                *reinterpret_cast<f32x4*>(orow)     = v0;
                *reinterpret_cast<f32x4*>(orow + 4) = v1;
            }
        }
    }
}

extern "C" void kernel_launch(void* const* d_in, const int* in_sizes, int n_in,
                              void* d_out, int out_size, void* d_ws, size_t ws_size,
                              hipStream_t stream) {
    const float* feat   = (const float*)d_in[0];
    const float* weight = (const float*)d_in[1];
    const int*   src    = (const int*)d_in[2];
    const int*   dst    = (const int*)d_in[3];
    const int*   et     = (const int*)d_in[4];
    float*       out    = (float*)d_out;

    if (ws_size < (size_t)WS_B) {
        hipMemsetAsync(d_out, 0, (size_t)out_size * sizeof(float), stream);
        hipLaunchKernelGGL(rgcn_edge_atomic, dim3(4096), dim3(256), 0, stream,
                           feat, weight, src, dst, et, out, N_EDGES / 4);
        return;
    }
    const bool use_h = (ws_size >= (size_t)WS_H);

    char* ws = (char*)d_ws;
    int*       relcur   = (int*)(ws + OFF_RELCUR);
    int*       bktcur   = (int*)(ws + OFF_BKTCUR);
    int*       tb       = (int*)(ws + OFF_TB);
    int*       dst_off  = (int*)(ws + OFF_DSTOFF);
    int*       relsrc   = (int*)(ws + OFF_RELSRC);
    int*       csr_y    = (int*)(ws + OFF_CSRY);
    int*       bucketed = (int*)(ws + OFF_BUCK);
    _Float16*  wT       = (_Float16*)(ws + OFF_WT);
    _Float16*  featH    = (_Float16*)(ws + OFF_FEATH);
    _Float16*  Y        = (_Float16*)(ws + (use_h ? OFF_Y_FULL : OFF_Y_BASE));

    int dev = 0, coop = 0;
    hipGetDevice(&dev);
    hipDeviceGetAttribute(&coop, hipDeviceAttributeCooperativeLaunch, dev);

    if (coop) {
        void* args[] = { (void*)&feat, (void*)&weight, (void*)&src, (void*)&dst, (void*)&et,
                         (void*)&wT, (void*)&featH, (void*)&relcur, (void*)&bktcur,
                         (void*)&relsrc, (void*)&bucketed, (void*)&csr_y, (void*)&dst_off,
                         (void*)&tb, (void*)&Y, (void*)&out };
        const void* fn = use_h ? (const void*)&mega<true> : (const void*)&mega<false>;
        hipError_t err = hipLaunchCooperativeKernel(fn, dim3(MEGA_BLOCKS), dim3(256),
                                                    args, 0, stream);
        if (err == hipSuccess) return;
        // fall through to multi-dispatch on failure
    }

    const int pre_blocks = N_RELS + (use_h ? FEATH_BLKS : 0);
    hipLaunchKernelGGL(kPre,       dim3(pre_blocks), dim3(256), 0, stream,
                       weight, wT, feat, featH, relcur, bktcur);
    hipLaunchKernelGGL(kC_scatter, dim3(NEBLK),    dim3(256), 0, stream,
                       src, dst, et, relcur, bktcur, relsrc, bucketed);
    hipLaunchKernelGGL(kD_csr,     dim3(NBKT + 1), dim3(256), 0, stream,
                       bucketed, bktcur, relcur, csr_y, dst_off, tb);
    if (use_h)
        hipLaunchKernelGGL((k4_gemm<true>),  dim3(NT_MAX), dim3(256), 0, stream,
                           feat, featH, wT, relsrc, relcur, tb, Y);
    else
        hipLaunchKernelGGL((k4_gemm<false>), dim3(NT_MAX), dim3(256), 0, stream,
                           feat, featH, wT, relsrc, relcur, tb, Y);
    hipLaunchKernelGGL(k5_reduce,  dim3((N_NODES + 3) / 4), dim3(256), 0, stream,
                       Y, csr_y, dst_off, bktcur, out);
}

// Round 17
// 406.078 us; speedup vs baseline: 1.4738x; 1.4738x over previous
//
#include <hip/hip_runtime.h>
#include <hip/hip_bf16.h>
#include <hip/hip_cooperative_groups.h>

namespace cg = cooperative_groups;

#define N_NODES 50000
#define N_EDGES 800000
#define N_RELS  32
#define D       64
#define TILE_M  128
#define NBKT    196                         // ceil(50000/256) dst buckets
#define EPB     2048                        // edges per virtual block in kC
#define NEBLK   ((N_EDGES + EPB - 1) / EPB) // 391
#define SEGCAP  27008                       // per-rel fixed cap (211*128)
#define CAPB    4608                        // per-bucket fixed cap
#define NT_MAX  (N_RELS * (SEGCAP / TILE_M))
#define FEATH_BLKS ((N_NODES * D / 8 + 255) / 256)   // 1563
#define MEGA_BLOCKS 512                     // 2 blocks/CU co-resident (grid.sync safe)

typedef _Float16 half8 __attribute__((ext_vector_type(8)));
typedef float    f32x4 __attribute__((ext_vector_type(4)));

// ---------------- workspace layout (bytes) — round-15 layout ----------------
#define OFF_RELCUR  0u          // 32 int
#define OFF_BKTCUR  128u        // 196 int
#define OFF_TB      912u        // 33 int
#define OFF_DSTOFF  1056u       // 50000 int
#define OFF_RELSRC  201056u     // 864256 int
#define OFF_CSRY    3658080u    // 903168 int
#define OFF_BUCK    7270752u    // 903168 int
#define OFF_WT      10883424u   // 32*64*64 fp16
#define OFF_FEATH   11145568u   // 50000*64 fp16
#define OFF_Y_FULL  17545568u   // 864256*64 fp16, rel-contiguous
#define OFF_Y_BASE  11145568u
#define WS_H        128170336u
#define WS_B        121770336u

// ---------------- fallback: atomic scatter path ----------------
__global__ __launch_bounds__(256) void rgcn_edge_atomic(
    const float* __restrict__ feat, const float* __restrict__ weight,
    const int* __restrict__ src, const int* __restrict__ dst,
    const int* __restrict__ et, float* __restrict__ out, int nquads)
{
    const int tid  = blockIdx.x * blockDim.x + threadIdx.x;
    const int wave = tid >> 6, lane = tid & 63;
    const int grp = lane >> 4, lg = lane & 15;
    const int wave_stride = (gridDim.x * blockDim.x) >> 6;
    for (int q = wave; q < nquads; q += wave_stride) {
        const int e = q * 4 + grp;
        const int s = src[e], d = dst[e], r = et[e];
        const float* w = weight + (size_t)r * D * D + lg * 4;
        float ax = 0.f, ay = 0.f, az = 0.f, aw = 0.f;
        #pragma unroll
        for (int i4 = 0; i4 < D / 4; ++i4) {
            const float4 f  = *reinterpret_cast<const float4*>(feat + (size_t)s * D + i4 * 4);
            const float4 w0 = *reinterpret_cast<const float4*>(w + (i4 * 4 + 0) * D);
            const float4 w1 = *reinterpret_cast<const float4*>(w + (i4 * 4 + 1) * D);
            const float4 w2 = *reinterpret_cast<const float4*>(w + (i4 * 4 + 2) * D);
            const float4 w3 = *reinterpret_cast<const float4*>(w + (i4 * 4 + 3) * D);
            ax += f.x*w0.x; ay += f.x*w0.y; az += f.x*w0.z; aw += f.x*w0.w;
            ax += f.y*w1.x; ay += f.y*w1.y; az += f.y*w1.z; aw += f.y*w1.w;
            ax += f.z*w2.x; ay += f.z*w2.y; az += f.z*w2.z; aw += f.z*w2.w;
            ax += f.w*w3.x; ay += f.w*w3.y; az += f.w*w3.z; aw += f.w*w3.w;
        }
        float* orow = out + (size_t)d * D + lg * 4;
        atomicAdd(orow + 0, ax); atomicAdd(orow + 1, ay);
        atomicAdd(orow + 2, az); atomicAdd(orow + 3, aw);
    }
}

// ============ standalone kernels (fallback path, round-15 proven) ============
__global__ __launch_bounds__(256) void kPre(const float* __restrict__ w,
                                            _Float16* __restrict__ wT,
                                            const float* __restrict__ feat,
                                            _Float16* __restrict__ featH,
                                            int* __restrict__ relcur,
                                            int* __restrict__ bktcur)
{
    const int t = threadIdx.x;
    if (blockIdx.x < N_RELS) {
        if (blockIdx.x == 0) {
            if (t < N_RELS)                relcur[t] = t * SEGCAP;
            else if (t < N_RELS + NBKT)    bktcur[t - N_RELS] = (t - N_RELS) * CAPB;
        }
        const int r = blockIdx.x;
        #pragma unroll
        for (int i = 0; i < 16; ++i) {
            int oidx = i * 256 + t;
            int o = oidx >> 6, k = oidx & 63;
            wT[(size_t)r * 4096 + oidx] = (_Float16)w[(size_t)r * 4096 + k * 64 + o];
        }
    } else {
        const int base = ((blockIdx.x - N_RELS) * 256 + t) * 8;
        if (base >= N_NODES * D) return;
        float4 f0 = *reinterpret_cast<const float4*>(feat + base);
        float4 f1 = *reinterpret_cast<const float4*>(feat + base + 4);
        half8 h;
        h[0]=(_Float16)f0.x; h[1]=(_Float16)f0.y; h[2]=(_Float16)f0.z; h[3]=(_Float16)f0.w;
        h[4]=(_Float16)f1.x; h[5]=(_Float16)f1.y; h[6]=(_Float16)f1.z; h[7]=(_Float16)f1.w;
        *reinterpret_cast<half8*>(featH + base) = h;
    }
}

__global__ __launch_bounds__(256) void kC_scatter(const int* __restrict__ src,
                                                  const int* __restrict__ dst,
                                                  const int* __restrict__ et,
                                                  int* __restrict__ relcur,
                                                  int* __restrict__ bktcur,
                                                  int* __restrict__ relsrc,
                                                  int* __restrict__ bucketed)
{
    __shared__ int lh[N_RELS],  lbase[N_RELS];
    __shared__ int lb[NBKT],    lbase2[NBKT];
    const int t = threadIdx.x;
    if (t < N_RELS) lh[t] = 0;
    if (t < NBKT)   lb[t] = 0;
    __syncthreads();
    const int base = blockIdx.x * EPB + t * 8;
    int r_[8], b_[8], s_[8], d_[8], sl[8], sl2[8];
    #pragma unroll
    for (int i = 0; i < 8; ++i) {
        int e = base + i;
        if (e < N_EDGES) {
            r_[i] = et[e]; s_[i] = src[e]; d_[i] = dst[e];
            b_[i] = d_[i] >> 8;
            sl[i]  = atomicAdd(&lh[r_[i]], 1);
            sl2[i] = atomicAdd(&lb[b_[i]], 1);
        }
    }
    __syncthreads();
    if (t < N_RELS && lh[t]) lbase[t]  = atomicAdd(&relcur[t], lh[t]);
    if (t < NBKT   && lb[t]) lbase2[t] = atomicAdd(&bktcur[t], lb[t]);
    __syncthreads();
    #pragma unroll
    for (int i = 0; i < 8; ++i) {
        int e = base + i;
        if (e < N_EDGES) {
            int j    = lbase[r_[i]] + sl[i];
            int pos2 = lbase2[b_[i]] + sl2[i];
            if (j < N_RELS * SEGCAP) relsrc[j] = s_[i];
            if (pos2 < NBKT * CAPB)
                bucketed[pos2] = ((d_[i] & 255) << 20) | j;
        }
    }
}

__global__ __launch_bounds__(256) void kD_csr(const int* __restrict__ bucketed,
                                              const int* __restrict__ bktcur,
                                              const int* __restrict__ relcur,
                                              int* __restrict__ csr_y,
                                              int* __restrict__ dst_off,
                                              int* __restrict__ tb)
{
    __shared__ int hist[256];
    __shared__ int s[256];
    const int b = blockIdx.x, t = threadIdx.x;
    if (b == NBKT) {
        int c = 0, w = 0;
        if (t < N_RELS) {
            c = min(relcur[t] - t * SEGCAP, SEGCAP);
            w = (c + TILE_M - 1) >> 7;
        }
        s[t] = (t < N_RELS) ? w : 0; __syncthreads();
        #pragma unroll
        for (int off = 1; off < N_RELS; off <<= 1) {
            int u = (t >= off && t < N_RELS) ? s[t - off] : 0;
            __syncthreads(); s[t] += u; __syncthreads();
        }
        if (t < N_RELS) tb[t] = s[t] - w;
        if (t == N_RELS - 1) tb[N_RELS] = s[t];
        return;
    }
    const int lo = b * CAPB;
    const int hi = min(bktcur[b], lo + CAPB);
    hist[t] = 0; __syncthreads();
    for (int p = lo + t; p < hi; p += 256)
        atomicAdd(&hist[bucketed[p] >> 20], 1);
    __syncthreads();
    int v = hist[t];
    s[t] = v; __syncthreads();
    #pragma unroll
    for (int off = 1; off < 256; off <<= 1) {
        int u = (t >= off) ? s[t - off] : 0;
        __syncthreads(); s[t] += u; __syncthreads();
    }
    int ex = lo + s[t] - v;
    int n = b * 256 + t;
    if (n < N_NODES) dst_off[n] = ex;
    hist[t] = ex;
    __syncthreads();
    for (int p = lo + t; p < hi; p += 256) {
        int key = bucketed[p];
        int pos = atomicAdd(&hist[key >> 20], 1);
        csr_y[pos] = key & 0xFFFFF;
    }
}

template <bool USE_H>
__global__ __launch_bounds__(256) void k4_gemm(const float* __restrict__ feat,
                                               const _Float16* __restrict__ featH,
                                               const _Float16* __restrict__ wT,
                                               const int* __restrict__ relsrc,
                                               const int* __restrict__ relcur,
                                               const int* __restrict__ tb,
                                               _Float16* __restrict__ Y)
{
    __shared__ _Float16 wL[64 * 64];
    const int b = blockIdx.x, t = threadIdx.x;
    int r = -1, ti = 0, t0 = 0;
    #pragma unroll
    for (int q = 0; q < N_RELS; ++q) {
        int t1 = tb[q + 1];
        if (b >= t0 && b < t1) { r = q; ti = b - t0; }
        t0 = t1;
    }
    if (r < 0) return;
    const int segend  = min(relcur[r], (r + 1) * SEGCAP);
    const int rowbase = r * SEGCAP + ti * TILE_M;
    {
        const _Float16* wsrc = wT + (size_t)r * 4096;
        #pragma unroll
        for (int it = 0; it < 2; ++it) {
            int L8 = it * 256 + t;
            int o = L8 >> 3, kcol = (L8 & 7) * 8;
            int baddr = (o * 128 + kcol * 2) ^ ((o & 7) << 4);
            *reinterpret_cast<half8*>(reinterpret_cast<char*>(wL) + baddr) =
                *reinterpret_cast<const half8*>(wsrc + L8 * 8);
        }
    }
    const int wid = t >> 6, l = t & 63;
    const int lrow = l & 15, lkb = l >> 4;
    half8 af[2][2];
    #pragma unroll
    for (int rt = 0; rt < 2; ++rt) {
        const int row = wid * 32 + rt * 16 + lrow;
        const int j = rowbase + row;
        const int sidx = (j < segend) ? relsrc[j] : 0;
        if (USE_H) {
            const _Float16* ar = featH + ((size_t)sidx << 6) + lkb * 8;
            af[rt][0] = *reinterpret_cast<const half8*>(ar);
            af[rt][1] = *reinterpret_cast<const half8*>(ar + 32);
        } else {
            const float* ar = feat + ((size_t)sidx << 6) + lkb * 8;
            float4 a0 = *reinterpret_cast<const float4*>(ar);
            float4 a1 = *reinterpret_cast<const float4*>(ar + 4);
            float4 a2 = *reinterpret_cast<const float4*>(ar + 32);
            float4 a3 = *reinterpret_cast<const float4*>(ar + 36);
            half8 h0, h1;
            h0[0]=(_Float16)a0.x; h0[1]=(_Float16)a0.y; h0[2]=(_Float16)a0.z; h0[3]=(_Float16)a0.w;
            h0[4]=(_Float16)a1.x; h0[5]=(_Float16)a1.y; h0[6]=(_Float16)a1.z; h0[7]=(_Float16)a1.w;
            h1[0]=(_Float16)a2.x; h1[1]=(_Float16)a2.y; h1[2]=(_Float16)a2.z; h1[3]=(_Float16)a2.w;
            h1[4]=(_Float16)a3.x; h1[5]=(_Float16)a3.y; h1[6]=(_Float16)a3.z; h1[7]=(_Float16)a3.w;
            af[rt][0] = h0; af[rt][1] = h1;
        }
    }
    __syncthreads();
    f32x4 acc[2][4] = {};
    #pragma unroll
    for (int ks = 0; ks < 2; ++ks) {
        half8 bfr[4];
        #pragma unroll
        for (int ct = 0; ct < 4; ++ct) {
            int n = ct * 16 + lrow;
            int baddr = (n * 128 + ks * 64 + lkb * 16) ^ ((n & 7) << 4);
            bfr[ct] = *reinterpret_cast<const half8*>(reinterpret_cast<const char*>(wL) + baddr);
        }
        #pragma unroll
        for (int rt = 0; rt < 2; ++rt)
            #pragma unroll
            for (int ct = 0; ct < 4; ++ct)
                acc[rt][ct] = __builtin_amdgcn_mfma_f32_16x16x32_f16(af[rt][ks], bfr[ct], acc[rt][ct], 0, 0, 0);
    }
    #pragma unroll
    for (int rt = 0; rt < 2; ++rt) {
        int lrow0 = wid * 32 + rt * 16 + (l >> 4) * 4;
        #pragma unroll
        for (int reg = 0; reg < 4; ++reg) {
            int lr = lrow0 + reg;
            int j = rowbase + lr;
            if (j < segend) {
                size_t yrow = (size_t)j * 64;
                #pragma unroll
                for (int ct = 0; ct < 4; ++ct)
                    Y[yrow + ct * 16 + lrow] = (_Float16)acc[rt][ct][reg];
            }
        }
    }
}

__global__ __launch_bounds__(256) void k5_reduce(const _Float16* __restrict__ Y,
                                                 const int* __restrict__ csr_y,
                                                 const int* __restrict__ dst_off,
                                                 const int* __restrict__ bktcur,
                                                 float* __restrict__ out)
{
    const int wid = threadIdx.x >> 6, l = threadIdx.x & 63;
    const int n = blockIdx.x * 4 + wid;
    if (n >= N_NODES) return;
    const int b = n >> 8;
    const int p0 = dst_off[n];
    int p1 = ((n & 255) == 255 || n == N_NODES - 1) ? bktcur[b] : dst_off[n + 1];
    p1 = min(p1, (b + 1) * CAPB);
    const int rg = l >> 3;
    const int cg = l & 7;
    float a[8] = {0,0,0,0,0,0,0,0};
    for (int p = p0; p < p1; p += 8) {
        int q = p + rg;
        if (q < p1) {
            int j = csr_y[q];
            half8 v = *reinterpret_cast<const half8*>(Y + (size_t)j * 64 + cg * 8);
            #pragma unroll
            for (int i = 0; i < 8; ++i) a[i] += (float)v[i];
        }
    }
    #pragma unroll
    for (int m = 8; m < 64; m <<= 1)
        #pragma unroll
        for (int i = 0; i < 8; ++i)
            a[i] += __shfl_xor(a[i], m, 64);
    if (rg == 0) {
        float* orow = out + (size_t)n * 64 + cg * 8;
        f32x4 v0 = {a[0], a[1], a[2], a[3]};
        f32x4 v1 = {a[4], a[5], a[6], a[7]};
        *reinterpret_cast<f32x4*>(orow)     = v0;
        *reinterpret_cast<f32x4*>(orow + 4) = v1;
    }
}

// ============ cooperative mega-kernel: all 5 phases, 4 grid syncs ============
// launch_bounds(256,2): 256-VGPR budget (no spills — round-16 failure was the
// (256,4) 64-VGPR cap spilling MFMA accumulators); 512 blocks = 2/CU resident.
template <bool USE_H>
__global__ __launch_bounds__(256, 2) void mega(
    const float* __restrict__ feat, const float* __restrict__ weight,
    const int* __restrict__ src, const int* __restrict__ dst, const int* __restrict__ et,
    _Float16* __restrict__ wT, _Float16* __restrict__ featH,
    int* __restrict__ relcur, int* __restrict__ bktcur,
    int* __restrict__ relsrc, int* __restrict__ bucketed,
    int* __restrict__ csr_y, int* __restrict__ dst_off, int* __restrict__ tb,
    _Float16* __restrict__ Y, float* __restrict__ out)
{
    cg::grid_group grid = cg::this_grid();
    const int t = threadIdx.x;
    __shared__ _Float16 wL[64 * 64];                 // 8 KB, unioned across phases
    int* ish = reinterpret_cast<int*>(wL);

    // ---- phase 1: cursors + wT transpose + featH convert ----
    const int pre_blocks = N_RELS + (USE_H ? FEATH_BLKS : 0);
    for (int b = blockIdx.x; b < pre_blocks; b += gridDim.x) {
        if (b < N_RELS) {
            if (b == 0) {
                if (t < N_RELS)             relcur[t] = t * SEGCAP;
                else if (t < N_RELS + NBKT) bktcur[t - N_RELS] = (t - N_RELS) * CAPB;
            }
            #pragma unroll
            for (int i = 0; i < 16; ++i) {
                int oidx = i * 256 + t;
                int o = oidx >> 6, k = oidx & 63;
                wT[(size_t)b * 4096 + oidx] = (_Float16)weight[(size_t)b * 4096 + k * 64 + o];
            }
        } else if (USE_H) {
            const int base = ((b - N_RELS) * 256 + t) * 8;
            if (base < N_NODES * D) {
                float4 f0 = *reinterpret_cast<const float4*>(feat + base);
                float4 f1 = *reinterpret_cast<const float4*>(feat + base + 4);
                half8 h;
                h[0]=(_Float16)f0.x; h[1]=(_Float16)f0.y; h[2]=(_Float16)f0.z; h[3]=(_Float16)f0.w;
                h[4]=(_Float16)f1.x; h[5]=(_Float16)f1.y; h[6]=(_Float16)f1.z; h[7]=(_Float16)f1.w;
                *reinterpret_cast<half8*>(featH + base) = h;
            }
        }
    }
    grid.sync();

    // ---- phase 2: scatter (rel segments + dst buckets) ----
    {
        int* lh  = ish;        int* lbA = ish + 32;
        int* lb  = ish + 64;   int* lbB = ish + 64 + NBKT;
        for (int b = blockIdx.x; b < NEBLK; b += gridDim.x) {
            __syncthreads();
            if (t < N_RELS) lh[t] = 0;
            if (t < NBKT)   lb[t] = 0;
            __syncthreads();
            const int base = b * EPB + t * 8;
            int r_[8], bb[8], s_[8], d_[8], sl[8], sl2[8];
            #pragma unroll
            for (int i = 0; i < 8; ++i) {
                int e = base + i;
                if (e < N_EDGES) {
                    r_[i] = et[e]; s_[i] = src[e]; d_[i] = dst[e];
                    bb[i] = d_[i] >> 8;
                    sl[i]  = atomicAdd(&lh[r_[i]], 1);
                    sl2[i] = atomicAdd(&lb[bb[i]], 1);
                }
            }
            __syncthreads();
            if (t < N_RELS && lh[t]) lbA[t] = atomicAdd(&relcur[t], lh[t]);
            if (t < NBKT   && lb[t]) lbB[t] = atomicAdd(&bktcur[t], lb[t]);
            __syncthreads();
            #pragma unroll
            for (int i = 0; i < 8; ++i) {
                int e = base + i;
                if (e < N_EDGES) {
                    int j    = lbA[r_[i]] + sl[i];
                    int pos2 = lbB[bb[i]] + sl2[i];
                    if (j < N_RELS * SEGCAP) relsrc[j] = s_[i];
                    if (pos2 < NBKT * CAPB)
                        bucketed[pos2] = ((d_[i] & 255) << 20) | j;
                }
            }
        }
    }
    grid.sync();

    // ---- phase 3: per-bucket counting sort -> csr_y/dst_off; +tile scan ----
    {
        int* hist = ish; int* s = ish + 256;
        for (int b = blockIdx.x; b < NBKT + 1; b += gridDim.x) {
            __syncthreads();
            if (b == NBKT) {
                int c = 0, w = 0;
                if (t < N_RELS) {
                    c = min(relcur[t] - t * SEGCAP, SEGCAP);
                    w = (c + TILE_M - 1) >> 7;
                }
                s[t] = (t < N_RELS) ? w : 0; __syncthreads();
                #pragma unroll
                for (int off = 1; off < N_RELS; off <<= 1) {
                    int u = (t >= off && t < N_RELS) ? s[t - off] : 0;
                    __syncthreads(); s[t] += u; __syncthreads();
                }
                if (t < N_RELS) tb[t] = s[t] - w;
                if (t == N_RELS - 1) tb[N_RELS] = s[t];
            } else {
                const int lo = b * CAPB;
                const int hi = min(bktcur[b], lo + CAPB);
                hist[t] = 0; __syncthreads();
                for (int p = lo + t; p < hi; p += 256)
                    atomicAdd(&hist[bucketed[p] >> 20], 1);
                __syncthreads();
                int v = hist[t];
                s[t] = v; __syncthreads();
                #pragma unroll
                for (int off = 1; off < 256; off <<= 1) {
                    int u = (t >= off) ? s[t - off] : 0;
                    __syncthreads(); s[t] += u; __syncthreads();
                }
                int ex = lo + s[t] - v;
                int n = b * 256 + t;
                if (n < N_NODES) dst_off[n] = ex;
                hist[t] = ex;
                __syncthreads();
                for (int p = lo + t; p < hi; p += 256) {
                    int key = bucketed[p];
                    int pos = atomicAdd(&hist[key >> 20], 1);
                    csr_y[pos] = key & 0xFFFFF;
                }
            }
        }
    }
    grid.sync();

    // ---- phase 4: per-relation MFMA GEMM -> Y (rel-contiguous) ----
    {
        const int tsum = tb[N_RELS];
        const int wid = t >> 6, l = t & 63;
        const int lrow = l & 15, lkb = l >> 4;
        for (int b = blockIdx.x; b < tsum; b += gridDim.x) {
            __syncthreads();
            int r = -1, ti = 0, t0 = 0;
            #pragma unroll
            for (int q = 0; q < N_RELS; ++q) {
                int t1 = tb[q + 1];
                if (b >= t0 && b < t1) { r = q; ti = b - t0; }
                t0 = t1;
            }
            if (r < 0) continue;
            const int segend  = min(relcur[r], (r + 1) * SEGCAP);
            const int rowbase = r * SEGCAP + ti * TILE_M;
            {
                const _Float16* wsrc = wT + (size_t)r * 4096;
                #pragma unroll
                for (int it = 0; it < 2; ++it) {
                    int L8 = it * 256 + t;
                    int o = L8 >> 3, kcol = (L8 & 7) * 8;
                    int baddr = (o * 128 + kcol * 2) ^ ((o & 7) << 4);
                    *reinterpret_cast<half8*>(reinterpret_cast<char*>(wL) + baddr) =
                        *reinterpret_cast<const half8*>(wsrc + L8 * 8);
                }
            }
            half8 af[2][2];
            #pragma unroll
            for (int rt = 0; rt < 2; ++rt) {
                const int row = wid * 32 + rt * 16 + lrow;
                const int j = rowbase + row;
                const int sidx = (j < segend) ? relsrc[j] : 0;
                if (USE_H) {
                    const _Float16* ar = featH + ((size_t)sidx << 6) + lkb * 8;
                    af[rt][0] = *reinterpret_cast<const half8*>(ar);
                    af[rt][1] = *reinterpret_cast<const half8*>(ar + 32);
                } else {
                    const float* ar = feat + ((size_t)sidx << 6) + lkb * 8;
                    float4 a0 = *reinterpret_cast<const float4*>(ar);
                    float4 a1 = *reinterpret_cast<const float4*>(ar + 4);
                    float4 a2 = *reinterpret_cast<const float4*>(ar + 32);
                    float4 a3 = *reinterpret_cast<const float4*>(ar + 36);
                    half8 h0, h1;
                    h0[0]=(_Float16)a0.x; h0[1]=(_Float16)a0.y; h0[2]=(_Float16)a0.z; h0[3]=(_Float16)a0.w;
                    h0[4]=(_Float16)a1.x; h0[5]=(_Float16)a1.y; h0[6]=(_Float16)a1.z; h0[7]=(_Float16)a1.w;
                    h1[0]=(_Float16)a2.x; h1[1]=(_Float16)a2.y; h1[2]=(_Float16)a2.z; h1[3]=(_Float16)a2.w;
                    h1[4]=(_Float16)a3.x; h1[5]=(_Float16)a3.y; h1[6]=(_Float16)a3.z; h1[7]=(_Float16)a3.w;
                    af[rt][0] = h0; af[rt][1] = h1;
                }
            }
            __syncthreads();
            f32x4 acc[2][4] = {};
            #pragma unroll
            for (int ks = 0; ks < 2; ++ks) {
                half8 bfr[4];
                #pragma unroll
                for (int ct = 0; ct < 4; ++ct) {
                    int n = ct * 16 + lrow;
                    int baddr = (n * 128 + ks * 64 + lkb * 16) ^ ((n & 7) << 4);
                    bfr[ct] = *reinterpret_cast<const half8*>(reinterpret_cast<const char*>(wL) + baddr);
                }
                #pragma unroll
                for (int rt = 0; rt < 2; ++rt)
                    #pragma unroll
                    for (int ct = 0; ct < 4; ++ct)
                        acc[rt][ct] = __builtin_amdgcn_mfma_f32_16x16x32_f16(af[rt][ks], bfr[ct], acc[rt][ct], 0, 0, 0);
            }
            #pragma unroll
            for (int rt = 0; rt < 2; ++rt) {
                int lrow0 = wid * 32 + rt * 16 + (l >> 4) * 4;
                #pragma unroll
                for (int reg = 0; reg < 4; ++reg) {
                    int lr = lrow0 + reg;
                    int j = rowbase + lr;
                    if (j < segend) {
                        size_t yrow = (size_t)j * 64;
                        #pragma unroll
                        for (int ct = 0; ct < 4; ++ct)
                            Y[yrow + ct * 16 + lrow] = (_Float16)acc[rt][ct][reg];
                    }
                }
            }
        }
    }
    grid.sync();

    // ---- phase 5: csr-indirect reduce -> out ----
    {
        const int wid = t >> 6, l = t & 63;
        const int rg = l >> 3, cg2 = l & 7;
        const int nvb = (N_NODES + 3) / 4;
        for (int vb = blockIdx.x; vb < nvb; vb += gridDim.x) {
            const int n = vb * 4 + wid;
            if (n >= N_NODES) continue;
            const int bkt = n >> 8;
            const int p0 = dst_off[n];
            int p1 = ((n & 255) == 255 || n == N_NODES - 1) ? bktcur[bkt] : dst_off[n + 1];
            p1 = min(p1, (bkt + 1) * CAPB);
            float a[8] = {0,0,0,0,0,0,0,0};
            for (int p = p0; p < p1; p += 8) {
                int q = p + rg;
                if (q < p1) {
                    int j = csr_y[q];
                    half8 v = *reinterpret_cast<const half8*>(Y + (size_t)j * 64 + cg2 * 8);
                    #pragma unroll
                    for (int i = 0; i < 8; ++i) a[i] += (float)v[i];
                }
            }
            #pragma unroll
            for (int m = 8; m < 64; m <<= 1)
                #pragma unroll
                for (int i = 0; i < 8; ++i)
                    a[i] += __shfl_xor(a[i], m, 64);
            if (rg == 0) {
                float* orow = out + (size_t)n * 64 + cg2 * 8;
                f32x4 v0 = {a[0], a[1], a[2], a[3]};
                f32x4 v1 = {a[4], a[5], a[6], a[7]};
                *reinterpret_cast<f32x4*>(orow)     = v0;
                *reinterpret_cast<f32x4*>(orow + 4) = v1;
            }
        }
    }
}

extern "C" void kernel_launch(void* const* d_in, const int* in_sizes, int n_in,
                              void* d_out, int out_size, void* d_ws, size_t ws_size,
                              hipStream_t stream) {
    const float* feat   = (const float*)d_in[0];
    const float* weight = (const float*)d_in[1];
    const int*   src    = (const int*)d_in[2];
    const int*   dst    = (const int*)d_in[3];
    const int*   et     = (const int*)d_in[4];
    float*       out    = (float*)d_out;

    if (ws_size < (size_t)WS_B) {
        hipMemsetAsync(d_out, 0, (size_t)out_size * sizeof(float), stream);
        hipLaunchKernelGGL(rgcn_edge_atomic, dim3(4096), dim3(256), 0, stream,
                           feat, weight, src, dst, et, out, N_EDGES / 4);
        return;
    }
    const bool use_h = (ws_size >= (size_t)WS_H);

    char* ws = (char*)d_ws;
    int*       relcur   = (int*)(ws + OFF_RELCUR);
    int*       bktcur   = (int*)(ws + OFF_BKTCUR);
    int*       tb       = (int*)(ws + OFF_TB);
    int*       dst_off  = (int*)(ws + OFF_DSTOFF);
    int*       relsrc   = (int*)(ws + OFF_RELSRC);
    int*       csr_y    = (int*)(ws + OFF_CSRY);
    int*       bucketed = (int*)(ws + OFF_BUCK);
    _Float16*  wT       = (_Float16*)(ws + OFF_WT);
    _Float16*  featH    = (_Float16*)(ws + OFF_FEATH);
    _Float16*  Y        = (_Float16*)(ws + (use_h ? OFF_Y_FULL : OFF_Y_BASE));

    int dev = 0, coop = 0;
    hipGetDevice(&dev);
    hipDeviceGetAttribute(&coop, hipDeviceAttributeCooperativeLaunch, dev);

    if (coop) {
        void* args[] = { (void*)&feat, (void*)&weight, (void*)&src, (void*)&dst, (void*)&et,
                         (void*)&wT, (void*)&featH, (void*)&relcur, (void*)&bktcur,
                         (void*)&relsrc, (void*)&bucketed, (void*)&csr_y, (void*)&dst_off,
                         (void*)&tb, (void*)&Y, (void*)&out };
        const void* fn = use_h ? (const void*)&mega<true> : (const void*)&mega<false>;
        hipError_t err = hipLaunchCooperativeKernel(fn, dim3(MEGA_BLOCKS), dim3(256),
                                                    args, 0, stream);
        if (err == hipSuccess) return;
        // fall through to multi-dispatch on failure
    }

    const int pre_blocks = N_RELS + (use_h ? FEATH_BLKS : 0);
    hipLaunchKernelGGL(kPre,       dim3(pre_blocks), dim3(256), 0, stream,
                       weight, wT, feat, featH, relcur, bktcur);
    hipLaunchKernelGGL(kC_scatter, dim3(NEBLK),    dim3(256), 0, stream,
                       src, dst, et, relcur, bktcur, relsrc, bucketed);
    hipLaunchKernelGGL(kD_csr,     dim3(NBKT + 1), dim3(256), 0, stream,
                       bucketed, bktcur, relcur, csr_y, dst_off, tb);
    if (use_h)
        hipLaunchKernelGGL((k4_gemm<true>),  dim3(NT_MAX), dim3(256), 0, stream,
                           feat, featH, wT, relsrc, relcur, tb, Y);
    else
        hipLaunchKernelGGL((k4_gemm<false>), dim3(NT_MAX), dim3(256), 0, stream,
                           feat, featH, wT, relsrc, relcur, tb, Y);
    hipLaunchKernelGGL(k5_reduce,  dim3((N_NODES + 3) / 4), dim3(256), 0, stream,
                       Y, csr_y, dst_off, bktcur, out);
}

// Round 18
// 108.525 us; speedup vs baseline: 5.5146x; 3.7418x over previous
//
#include <hip/hip_runtime.h>
#include <hip/hip_bf16.h>

#define N_NODES 50000
#define N_EDGES 800000
#define N_RELS  32
#define D       64
#define TILE_M  128
#define NBKT    196                         // ceil(50000/256) dst buckets
#define EPB     2048                        // edges per block in kC
#define NEBLK   ((N_EDGES + EPB - 1) / EPB) // 391
#define SEGCAP  27008                       // per-rel fixed cap (211*128; mean 25000, +12.9σ)
#define CAPB    4608                        // per-bucket fixed cap (mean 4082, +8.2σ)
#define NT_MAX  (N_RELS * (SEGCAP / TILE_M))// 6752 tile upper bound
#define FEATH_BLKS ((N_NODES * D / 8 + 255) / 256)   // 1563

typedef _Float16 half8 __attribute__((ext_vector_type(8)));
typedef float    f32x4 __attribute__((ext_vector_type(4)));

// ---------------- workspace layout (bytes) ----------------
#define OFF_RELCUR  0u          // 32 int  (init to r*SEGCAP by kPre)
#define OFF_BKTCUR  128u        // 196 int (init to b*CAPB by kPre)
#define OFF_TB      912u        // 33 int  (pad to 1056 after)
#define OFF_DSTOFF  1056u       // 50000 int
#define OFF_RELSRC  201056u     // 864256 int (32 segments x 27008)
#define OFF_J2POS   3658080u    // 864256 int
#define OFF_BUCK    7115104u    // 903168 int (196 x 4608)
#define OFF_WT      10727776u   // 32*64*64 fp16
#define OFF_FEATH   10989920u   // 50000*64 fp16 (full tier only)
#define OFF_Y_FULL  17389920u   // 903168*64 fp16
#define OFF_Y_BASE  10989920u   // Y when featH doesn't fit
#define WS_H        132995424u
#define WS_B        126595424u

// ---------------- fallback: atomic scatter path ----------------
__global__ __launch_bounds__(256) void rgcn_edge_atomic(
    const float* __restrict__ feat, const float* __restrict__ weight,
    const int* __restrict__ src, const int* __restrict__ dst,
    const int* __restrict__ et, float* __restrict__ out, int nquads)
{
    const int tid  = blockIdx.x * blockDim.x + threadIdx.x;
    const int wave = tid >> 6, lane = tid & 63;
    const int grp = lane >> 4, lg = lane & 15;
    const int wave_stride = (gridDim.x * blockDim.x) >> 6;
    for (int q = wave; q < nquads; q += wave_stride) {
        const int e = q * 4 + grp;
        const int s = src[e], d = dst[e], r = et[e];
        const float* w = weight + (size_t)r * D * D + lg * 4;
        float ax = 0.f, ay = 0.f, az = 0.f, aw = 0.f;
        #pragma unroll
        for (int i4 = 0; i4 < D / 4; ++i4) {
            const float4 f  = *reinterpret_cast<const float4*>(feat + (size_t)s * D + i4 * 4);
            const float4 w0 = *reinterpret_cast<const float4*>(w + (i4 * 4 + 0) * D);
            const float4 w1 = *reinterpret_cast<const float4*>(w + (i4 * 4 + 1) * D);
            const float4 w2 = *reinterpret_cast<const float4*>(w + (i4 * 4 + 2) * D);
            const float4 w3 = *reinterpret_cast<const float4*>(w + (i4 * 4 + 3) * D);
            ax += f.x*w0.x; ay += f.x*w0.y; az += f.x*w0.z; aw += f.x*w0.w;
            ax += f.y*w1.x; ay += f.y*w1.y; az += f.y*w1.z; aw += f.y*w1.w;
            ax += f.z*w2.x; ay += f.z*w2.y; az += f.z*w2.z; aw += f.z*w2.w;
            ax += f.w*w3.x; ay += f.w*w3.y; az += f.w*w3.z; aw += f.w*w3.w;
        }
        float* orow = out + (size_t)d * D + lg * 4;
        atomicAdd(orow + 0, ax); atomicAdd(orow + 1, ay);
        atomicAdd(orow + 2, az); atomicAdd(orow + 3, aw);
    }
}

// ---------------- kPre: init cursors + W->W^T fp16 + feat->fp16 -------------
__global__ __launch_bounds__(256) void kPre(const float* __restrict__ w,
                                            _Float16* __restrict__ wT,
                                            const float* __restrict__ feat,
                                            _Float16* __restrict__ featH,
                                            int* __restrict__ relcur,
                                            int* __restrict__ bktcur)
{
    const int t = threadIdx.x;
    if (blockIdx.x < N_RELS) {
        if (blockIdx.x == 0) {
            if (t < N_RELS)                relcur[t] = t * SEGCAP;
            else if (t < N_RELS + NBKT)    bktcur[t - N_RELS] = (t - N_RELS) * CAPB;
        }
        const int r = blockIdx.x;
        #pragma unroll
        for (int i = 0; i < 16; ++i) {
            int oidx = i * 256 + t;
            int o = oidx >> 6, k = oidx & 63;
            wT[(size_t)r * 4096 + oidx] = (_Float16)w[(size_t)r * 4096 + k * 64 + o];
        }
    } else {
        const int base = ((blockIdx.x - N_RELS) * 256 + t) * 8;
        if (base >= N_NODES * D) return;
        float4 f0 = *reinterpret_cast<const float4*>(feat + base);
        float4 f1 = *reinterpret_cast<const float4*>(feat + base + 4);
        half8 h;
        h[0]=(_Float16)f0.x; h[1]=(_Float16)f0.y; h[2]=(_Float16)f0.z; h[3]=(_Float16)f0.w;
        h[4]=(_Float16)f1.x; h[5]=(_Float16)f1.y; h[6]=(_Float16)f1.z; h[7]=(_Float16)f1.w;
        *reinterpret_cast<half8*>(featH + base) = h;
    }
}

// ---------------- kC: rel-scatter + dst-bucket scatter (fixed-cap bases) ----
__global__ __launch_bounds__(256) void kC_scatter(const int* __restrict__ src,
                                                  const int* __restrict__ dst,
                                                  const int* __restrict__ et,
                                                  int* __restrict__ relcur,
                                                  int* __restrict__ bktcur,
                                                  int* __restrict__ relsrc,
                                                  int* __restrict__ bucketed)
{
    __shared__ int lh[N_RELS],  lbase[N_RELS];
    __shared__ int lb[NBKT],    lbase2[NBKT];
    const int t = threadIdx.x;
    if (t < N_RELS) lh[t] = 0;
    if (t < NBKT)   lb[t] = 0;
    __syncthreads();
    const int base = blockIdx.x * EPB + t * 8;
    int r_[8], b_[8], s_[8], d_[8], sl[8], sl2[8];
    #pragma unroll
    for (int i = 0; i < 8; ++i) {
        int e = base + i;
        if (e < N_EDGES) {
            r_[i] = et[e]; s_[i] = src[e]; d_[i] = dst[e];
            b_[i] = d_[i] >> 8;
            sl[i]  = atomicAdd(&lh[r_[i]], 1);
            sl2[i] = atomicAdd(&lb[b_[i]], 1);
        }
    }
    __syncthreads();
    if (t < N_RELS && lh[t]) lbase[t]  = atomicAdd(&relcur[t], lh[t]);
    if (t < NBKT   && lb[t]) lbase2[t] = atomicAdd(&bktcur[t], lb[t]);
    __syncthreads();
    #pragma unroll
    for (int i = 0; i < 8; ++i) {
        int e = base + i;
        if (e < N_EDGES) {
            int j    = lbase[r_[i]] + sl[i];
            int pos2 = lbase2[b_[i]] + sl2[i];
            if (j < N_RELS * SEGCAP) relsrc[j] = s_[i];            // cap guard (~13σ)
            if (pos2 < NBKT * CAPB)
                bucketed[pos2] = ((d_[i] & 255) << 20) | j;
        }
    }
}

// ---------------- kD': per-bucket counting sort + (block NBKT) tile scan ----
__global__ __launch_bounds__(256) void kD_csr(const int* __restrict__ bucketed,
                                              const int* __restrict__ bktcur,
                                              const int* __restrict__ relcur,
                                              int* __restrict__ j2pos,
                                              int* __restrict__ dst_off,
                                              int* __restrict__ tb)
{
    __shared__ int hist[256];
    __shared__ int s[256];
    const int b = blockIdx.x, t = threadIdx.x;
    if (b == NBKT) {
        // tile-table scan from final rel cursors
        int c = 0, w = 0;
        if (t < N_RELS) {
            c = min(relcur[t] - t * SEGCAP, SEGCAP);
            w = (c + TILE_M - 1) >> 7;
        }
        s[t] = (t < N_RELS) ? w : 0; __syncthreads();
        #pragma unroll
        for (int off = 1; off < N_RELS; off <<= 1) {
            int u = (t >= off && t < N_RELS) ? s[t - off] : 0;
            __syncthreads(); s[t] += u; __syncthreads();
        }
        if (t < N_RELS) tb[t] = s[t] - w;
        if (t == N_RELS - 1) tb[N_RELS] = s[t];
        return;
    }
    const int lo = b * CAPB;
    const int hi = min(bktcur[b], lo + CAPB);
    hist[t] = 0; __syncthreads();
    for (int p = lo + t; p < hi; p += 256)
        atomicAdd(&hist[bucketed[p] >> 20], 1);
    __syncthreads();
    int v = hist[t];
    s[t] = v; __syncthreads();
    #pragma unroll
    for (int off = 1; off < 256; off <<= 1) {
        int u = (t >= off) ? s[t - off] : 0;
        __syncthreads(); s[t] += u; __syncthreads();
    }
    int ex = lo + s[t] - v;
    int n = b * 256 + t;
    if (n < N_NODES) dst_off[n] = ex;
    hist[t] = ex;
    __syncthreads();
    for (int p = lo + t; p < hi; p += 256) {
        int key = bucketed[p];
        int pos = atomicAdd(&hist[key >> 20], 1);
        j2pos[key & 0xFFFFF] = pos;        // rel-index j -> dst-CSR slot
    }
}

// ---------------- K4: per-relation GEMM via MFMA -> Y (dst-ordered) ---------
// TILE_M=128, 4 waves. Direct-from-global A fragments; W^T + ypos in LDS.
template <bool USE_H>
__global__ __launch_bounds__(256) void k4_gemm(const float* __restrict__ feat,
                                               const _Float16* __restrict__ featH,
                                               const _Float16* __restrict__ wT,
                                               const int* __restrict__ relsrc,
                                               const int* __restrict__ j2pos,
                                               const int* __restrict__ relcur,
                                               const int* __restrict__ tb,
                                               _Float16* __restrict__ Y)
{
    __shared__ _Float16 wL[64 * 64];       // XOR-swizzled [out][k], 8 KB
    __shared__ int      ypos[TILE_M];
    const int b = blockIdx.x, t = threadIdx.x;

    int r = -1, ti = 0, t0 = 0;
    #pragma unroll
    for (int q = 0; q < N_RELS; ++q) {
        int t1 = tb[q + 1];
        if (b >= t0 && b < t1) { r = q; ti = b - t0; }
        t0 = t1;
    }
    if (r < 0) return;
    const int segend  = min(relcur[r], (r + 1) * SEGCAP);
    const int rowbase = r * SEGCAP + ti * TILE_M;

    if (t < TILE_M) {
        const int j = rowbase + t;
        ypos[t] = (j < segend) ? j2pos[j] : 0;
    } else {
        const _Float16* wsrc = wT + (size_t)r * 4096;
        const int tt = t - 128;
        #pragma unroll
        for (int it = 0; it < 4; ++it) {
            int L8 = it * 128 + tt;
            int o = L8 >> 3, kcol = (L8 & 7) * 8;
            int baddr = (o * 128 + kcol * 2) ^ ((o & 7) << 4);
            *reinterpret_cast<half8*>(reinterpret_cast<char*>(wL) + baddr) =
                *reinterpret_cast<const half8*>(wsrc + L8 * 8);
        }
    }

    const int wid = t >> 6, l = t & 63;
    const int lrow = l & 15, lkb = l >> 4;

    half8 af[2][2];                        // [rt][ks]
    #pragma unroll
    for (int rt = 0; rt < 2; ++rt) {
        const int row = wid * 32 + rt * 16 + lrow;
        const int j = rowbase + row;
        const int sidx = (j < segend) ? relsrc[j] : 0;
        if (USE_H) {
            const _Float16* ar = featH + ((size_t)sidx << 6) + lkb * 8;
            af[rt][0] = *reinterpret_cast<const half8*>(ar);
            af[rt][1] = *reinterpret_cast<const half8*>(ar + 32);
        } else {
            const float* ar = feat + ((size_t)sidx << 6) + lkb * 8;
            float4 a0 = *reinterpret_cast<const float4*>(ar);
            float4 a1 = *reinterpret_cast<const float4*>(ar + 4);
            float4 a2 = *reinterpret_cast<const float4*>(ar + 32);
            float4 a3 = *reinterpret_cast<const float4*>(ar + 36);
            half8 h0, h1;
            h0[0]=(_Float16)a0.x; h0[1]=(_Float16)a0.y; h0[2]=(_Float16)a0.z; h0[3]=(_Float16)a0.w;
            h0[4]=(_Float16)a1.x; h0[5]=(_Float16)a1.y; h0[6]=(_Float16)a1.z; h0[7]=(_Float16)a1.w;
            h1[0]=(_Float16)a2.x; h1[1]=(_Float16)a2.y; h1[2]=(_Float16)a2.z; h1[3]=(_Float16)a2.w;
            h1[4]=(_Float16)a3.x; h1[5]=(_Float16)a3.y; h1[6]=(_Float16)a3.z; h1[7]=(_Float16)a3.w;
            af[rt][0] = h0; af[rt][1] = h1;
        }
    }
    __syncthreads();

    f32x4 acc[2][4] = {};
    #pragma unroll
    for (int ks = 0; ks < 2; ++ks) {
        half8 bfr[4];
        #pragma unroll
        for (int ct = 0; ct < 4; ++ct) {
            int n = ct * 16 + lrow;
            int baddr = (n * 128 + ks * 64 + lkb * 16) ^ ((n & 7) << 4);
            bfr[ct] = *reinterpret_cast<const half8*>(reinterpret_cast<const char*>(wL) + baddr);
        }
        #pragma unroll
        for (int rt = 0; rt < 2; ++rt)
            #pragma unroll
            for (int ct = 0; ct < 4; ++ct)
                acc[rt][ct] = __builtin_amdgcn_mfma_f32_16x16x32_f16(af[rt][ks], bfr[ct], acc[rt][ct], 0, 0, 0);
    }
    #pragma unroll
    for (int rt = 0; rt < 2; ++rt) {
        int lrow0 = wid * 32 + rt * 16 + (l >> 4) * 4;
        #pragma unroll
        for (int reg = 0; reg < 4; ++reg) {
            int lr = lrow0 + reg;
            if (rowbase + lr < segend) {
                size_t yrow = (size_t)ypos[lr] * 64;
                #pragma unroll
                for (int ct = 0; ct < 4; ++ct)
                    Y[yrow + ct * 16 + lrow] = (_Float16)acc[rt][ct][reg];
            }
        }
    }
}

// ---------------- K5: vectorized streaming reduce over dst-ordered Y --------
__global__ __launch_bounds__(256) void k5_reduce(const _Float16* __restrict__ Y,
                                                 const int* __restrict__ dst_off,
                                                 const int* __restrict__ bktcur,
                                                 float* __restrict__ out)
{
    const int wid = threadIdx.x >> 6, l = threadIdx.x & 63;
    const int n = blockIdx.x * 4 + wid;
    if (n >= N_NODES) return;
    const int b = n >> 8;
    const int p0 = dst_off[n];
    int p1 = ((n & 255) == 255 || n == N_NODES - 1) ? bktcur[b] : dst_off[n + 1];
    p1 = min(p1, (b + 1) * CAPB);
    const int rg = l >> 3;
    const int cg = l & 7;
    float a[8] = {0,0,0,0,0,0,0,0};
    for (int p = p0; p < p1; p += 8) {
        int row = p + rg;
        if (row < p1) {
            half8 v = *reinterpret_cast<const half8*>(Y + (size_t)row * 64 + cg * 8);
            #pragma unroll
            for (int i = 0; i < 8; ++i) a[i] += (float)v[i];
        }
    }
    #pragma unroll
    for (int m = 8; m < 64; m <<= 1)
        #pragma unroll
        for (int i = 0; i < 8; ++i)
            a[i] += __shfl_xor(a[i], m, 64);
    if (rg == 0) {
        float* orow = out + (size_t)n * 64 + cg * 8;
        f32x4 v0 = {a[0], a[1], a[2], a[3]};
        f32x4 v1 = {a[4], a[5], a[6], a[7]};
        *reinterpret_cast<f32x4*>(orow)     = v0;
        *reinterpret_cast<f32x4*>(orow + 4) = v1;
    }
}

extern "C" void kernel_launch(void* const* d_in, const int* in_sizes, int n_in,
                              void* d_out, int out_size, void* d_ws, size_t ws_size,
                              hipStream_t stream) {
    const float* feat   = (const float*)d_in[0];
    const float* weight = (const float*)d_in[1];
    const int*   src    = (const int*)d_in[2];
    const int*   dst    = (const int*)d_in[3];
    const int*   et     = (const int*)d_in[4];
    float*       out    = (float*)d_out;

    if (ws_size < (size_t)WS_B) {
        hipMemsetAsync(d_out, 0, (size_t)out_size * sizeof(float), stream);
        hipLaunchKernelGGL(rgcn_edge_atomic, dim3(4096), dim3(256), 0, stream,
                           feat, weight, src, dst, et, out, N_EDGES / 4);
        return;
    }
    const bool use_h = (ws_size >= (size_t)WS_H);

    char* ws = (char*)d_ws;
    int*       relcur   = (int*)(ws + OFF_RELCUR);
    int*       bktcur   = (int*)(ws + OFF_BKTCUR);
    int*       tb       = (int*)(ws + OFF_TB);
    int*       dst_off  = (int*)(ws + OFF_DSTOFF);
    int*       relsrc   = (int*)(ws + OFF_RELSRC);
    int*       j2pos    = (int*)(ws + OFF_J2POS);
    int*       bucketed = (int*)(ws + OFF_BUCK);
    _Float16*  wT       = (_Float16*)(ws + OFF_WT);
    _Float16*  featH    = (_Float16*)(ws + OFF_FEATH);
    _Float16*  Y        = (_Float16*)(ws + (use_h ? OFF_Y_FULL : OFF_Y_BASE));

    const int pre_blocks = N_RELS + (use_h ? FEATH_BLKS : 0);
    hipLaunchKernelGGL(kPre,       dim3(pre_blocks), dim3(256), 0, stream,
                       weight, wT, feat, featH, relcur, bktcur);
    hipLaunchKernelGGL(kC_scatter, dim3(NEBLK),    dim3(256), 0, stream,
                       src, dst, et, relcur, bktcur, relsrc, bucketed);
    hipLaunchKernelGGL(kD_csr,     dim3(NBKT + 1), dim3(256), 0, stream,
                       bucketed, bktcur, relcur, j2pos, dst_off, tb);
    if (use_h)
        hipLaunchKernelGGL((k4_gemm<true>),  dim3(NT_MAX), dim3(256), 0, stream,
                           feat, featH, wT, relsrc, j2pos, relcur, tb, Y);
    else
        hipLaunchKernelGGL((k4_gemm<false>), dim3(NT_MAX), dim3(256), 0, stream,
                           feat, featH, wT, relsrc, j2pos, relcur, tb, Y);
    hipLaunchKernelGGL(k5_reduce,  dim3((N_NODES + 3) / 4), dim3(256), 0, stream,
                       Y, dst_off, bktcur, out);
}